// Round 3
// baseline (811.334 us; speedup 1.0000x reference)
//
#include <hip/hip_runtime.h>

// B=2, L=4096, C=512, H=8, hd=64. Inputs/outputs FLOAT32 (per reference).
// Compute in bf16 MFMA with f32 accumulate (threshold = 2% of max|ref|).
//
// ws layout (bytes): o (B,L,C) bf16 = 8 MiB, then per-group q,k (B,G,L,hd)
// and vt (B,G,hd,L) bf16 = 3*G MiB. Total 8 + 3G MiB, G picked from ws_size.

typedef __attribute__((ext_vector_type(8))) short short8;   // 8 bf16
typedef __attribute__((ext_vector_type(4))) float floatx4;  // MFMA C/D

#define MFMA(a, b, c) __builtin_amdgcn_mfma_f32_16x16x32_bf16((a), (b), (c), 0, 0, 0)

__device__ __forceinline__ unsigned short f2bf(float f) {
    unsigned int u = __builtin_bit_cast(unsigned int, f);
    return (unsigned short)((u + 0x7fffu + ((u >> 16) & 1u)) >> 16);  // RTNE
}
__device__ __forceinline__ float clampf(float v, float lim) {
    return fminf(fmaxf(v, -lim), lim);  // launders NaN -> -lim (diagnostic)
}
// Load 8 consecutive f32, convert to bf16 MFMA fragment (RTNE).
__device__ __forceinline__ short8 load_cvt8(const float* __restrict__ p) {
    float4 a = *(const float4*)p;
    float4 b = *(const float4*)(p + 4);
    short8 r;
    r[0] = (short)f2bf(a.x); r[1] = (short)f2bf(a.y);
    r[2] = (short)f2bf(a.z); r[3] = (short)f2bf(a.w);
    r[4] = (short)f2bf(b.x); r[5] = (short)f2bf(b.y);
    r[6] = (short)f2bf(b.z); r[7] = (short)f2bf(b.w);
    return r;
}

// ---------------------------------------------------------------------------
// Kernel 1: qkv = x @ qkv_w.T + b for G heads from h0; RoPE q,k; v transposed.
// blockIdx.y in [0,3G): sec = y/G (0=q,1=k,2=v), head = h0 + y%G.
// Block 256 thr = 4 waves; wave tile 16(M) x 64(N); block M=64.
// ---------------------------------------------------------------------------
__global__ __launch_bounds__(256) void qkv_rope(
    const float* __restrict__ x,      // (8192, 512) f32
    const float* __restrict__ w,      // (1536, 512) f32
    const float* __restrict__ bias,   // (1536,) f32
    ushort* __restrict__ q, ushort* __restrict__ k, ushort* __restrict__ vt,
    int G, int h0)
{
    const int w_id = threadIdx.x >> 6;
    const int lane = threadIdx.x & 63;
    const int lr = lane & 15, quad = lane >> 4;
    const int m0 = blockIdx.x * 64 + w_id * 16;
    const int sec = blockIdx.y / G, hl = blockIdx.y % G;
    const int wc0 = sec * 512 + (h0 + hl) * 64;   // column base in qkv dim

    floatx4 acc[4] = {};
    const float* xrow = x + (size_t)(m0 + lr) * 512 + quad * 8;
    for (int kk = 0; kk < 512; kk += 32) {
        short8 a = load_cvt8(xrow + kk);
#pragma unroll
        for (int nt = 0; nt < 4; ++nt) {
            short8 b = load_cvt8(w + (size_t)(wc0 + nt * 16 + lr) * 512 + kk + quad * 8);
            acc[nt] = MFMA(a, b, acc[nt]);
        }
    }

#pragma unroll
    for (int nt = 0; nt < 4; ++nt) {
        const int d = nt * 16 + lr;                // dim within head
        const float bv = bias[wc0 + d];
#pragma unroll
        for (int r = 0; r < 4; ++r) {
            const int row = m0 + quad * 4 + r;     // global token row
            const int b_ = row >> 12;              // batch
            const int pos = row & 4095;            // position
            float val = acc[nt][r] + bv;
            const size_t bhl = (size_t)(b_ * G + hl);
            if (sec < 2) {
                float partner = __shfl_xor(val, 1);  // element d^1 (lane lr^1)
                float invf = exp2f(-0.41524101186f * (float)(d & 31)); // 1e4^(-2j/64)
                float sv, cv;
                sincosf((float)pos * invf, &sv, &cv);
                float rh = (d & 1) ? partner : -partner;  // rotate_half
                ushort* dst = (sec == 0) ? q : k;
                dst[(bhl * 4096 + pos) * 64 + d] = f2bf(val * cv + rh * sv);
            } else {
                vt[(bhl * 64 + d) * 4096 + pos] = f2bf(val);
            }
        }
    }
}

// ---------------------------------------------------------------------------
// Kernel 2: flash attention. One wave = 16 q-rows; 4096 keys in chunks of 32,
// online softmax; P round-trips LDS (stride 56, 16B-aligned b128 reads).
// Output o: bf16 (B, L, H*hd) in ws at head h0+hl.
// ---------------------------------------------------------------------------
__global__ __launch_bounds__(256) void flash_attn(
    const ushort* __restrict__ q, const ushort* __restrict__ k,
    const ushort* __restrict__ vt, ushort* __restrict__ o,
    int G, int h0)
{
    __shared__ __align__(16) ushort plds[4][16 * 56];
    const int w_id = threadIdx.x >> 6;
    const int lane = threadIdx.x & 63;
    const int lr = lane & 15, quad = lane >> 4;
    const int bhl = blockIdx.y;                 // b*G + hl
    const int b_ = bhl / G, hl = bhl % G;
    const int q0 = blockIdx.x * 64 + w_id * 16;

    const ushort* qp = q + (size_t)bhl * 262144;
    const ushort* kp = k + (size_t)bhl * 262144;
    const ushort* vp = vt + (size_t)bhl * 262144;
    ushort* op = o + (size_t)b_ * 4096 * 512 + (size_t)(h0 + hl) * 64;

    short8 qf0 = *(const short8*)(qp + (size_t)(q0 + lr) * 64 + quad * 8);
    short8 qf1 = *(const short8*)(qp + (size_t)(q0 + lr) * 64 + 32 + quad * 8);

    floatx4 oacc[4] = {};
    float mrow[4] = {-INFINITY, -INFINITY, -INFINITY, -INFINITY};
    float lrow[4] = {0.f, 0.f, 0.f, 0.f};
    ushort* pw = &plds[w_id][0];

    for (int kk = 0; kk < 4096; kk += 32) {
        floatx4 s0 = {}, s1 = {};
        {
            const ushort* kb0 = kp + (size_t)(kk + lr) * 64 + quad * 8;
            const ushort* kb1 = kp + (size_t)(kk + 16 + lr) * 64 + quad * 8;
            short8 k00 = *(const short8*)(kb0);
            short8 k01 = *(const short8*)(kb0 + 32);
            short8 k10 = *(const short8*)(kb1);
            short8 k11 = *(const short8*)(kb1 + 32);
            s0 = MFMA(qf0, k00, s0);
            s0 = MFMA(qf1, k01, s0);
            s1 = MFMA(qf0, k10, s1);
            s1 = MFMA(qf1, k11, s1);
        }
        float p0[4], p1[4], alpha[4];
#pragma unroll
        for (int r = 0; r < 4; ++r) {
            float a0 = clampf(s0[r] * 0.125f, 80.f);
            float a1 = clampf(s1[r] * 0.125f, 80.f);
            float mx = fmaxf(a0, a1);
            mx = fmaxf(mx, __shfl_xor(mx, 1));
            mx = fmaxf(mx, __shfl_xor(mx, 2));
            mx = fmaxf(mx, __shfl_xor(mx, 4));
            mx = fmaxf(mx, __shfl_xor(mx, 8));
            float mn = fmaxf(mrow[r], mx);
            alpha[r] = __expf(mrow[r] - mn);   // exp(-inf)=0 first chunk
            mrow[r] = mn;
            p0[r] = __expf(a0 - mn);
            p1[r] = __expf(a1 - mn);
            float rs = p0[r] + p1[r];
            rs += __shfl_xor(rs, 1);
            rs += __shfl_xor(rs, 2);
            rs += __shfl_xor(rs, 4);
            rs += __shfl_xor(rs, 8);
            lrow[r] = lrow[r] * alpha[r] + rs;
        }
#pragma unroll
        for (int nt = 0; nt < 4; ++nt)
#pragma unroll
            for (int r = 0; r < 4; ++r) oacc[nt][r] *= alpha[r];

        // P -> LDS (C-layout rows = query, cols = key), read as PV A-operand
#pragma unroll
        for (int r = 0; r < 4; ++r) {
            pw[(quad * 4 + r) * 56 + lr] = f2bf(p0[r]);
            pw[(quad * 4 + r) * 56 + 16 + lr] = f2bf(p1[r]);
        }
        __syncthreads();
        short8 pf = *(const short8*)(pw + lr * 56 + quad * 8);
#pragma unroll
        for (int nt = 0; nt < 4; ++nt) {
            short8 vf = *(const short8*)(vp + (size_t)(nt * 16 + lr) * 4096 + kk + quad * 8);
            oacc[nt] = MFMA(pf, vf, oacc[nt]);
        }
        __syncthreads();
    }

#pragma unroll
    for (int r = 0; r < 4; ++r) {
        float inv = 1.0f / lrow[r];
#pragma unroll
        for (int nt = 0; nt < 4; ++nt)
            op[(size_t)(q0 + quad * 4 + r) * 512 + nt * 16 + lr] =
                f2bf(clampf(oacc[nt][r] * inv, 1e4f));
    }
}

// ---------------------------------------------------------------------------
// Kernel 3: out(f32) = o(bf16) @ proj_w.T + proj_b. Out-of-place (no race).
// ---------------------------------------------------------------------------
__global__ __launch_bounds__(256) void proj_gemm(
    const ushort* __restrict__ o,      // (8192, 512) bf16 in ws
    const float* __restrict__ w,       // (512, 512) f32
    const float* __restrict__ bias,    // (512,) f32
    float* __restrict__ out)           // (8192, 512) f32
{
    const int w_id = threadIdx.x >> 6;
    const int lane = threadIdx.x & 63;
    const int lr = lane & 15, quad = lane >> 4;
    const int m0 = blockIdx.x * 64 + w_id * 16;
    const int n0 = blockIdx.y * 64;

    floatx4 acc[4] = {};
    const ushort* orow = o + (size_t)(m0 + lr) * 512 + quad * 8;
    for (int kk = 0; kk < 512; kk += 32) {
        short8 a = *(const short8*)(orow + kk);
#pragma unroll
        for (int nt = 0; nt < 4; ++nt) {
            short8 b = load_cvt8(w + (size_t)(n0 + nt * 16 + lr) * 512 + kk + quad * 8);
            acc[nt] = MFMA(a, b, acc[nt]);
        }
    }
#pragma unroll
    for (int nt = 0; nt < 4; ++nt) {
        const int n = n0 + nt * 16 + lr;
        const float bv = bias[n];
#pragma unroll
        for (int r = 0; r < 4; ++r)
            out[(size_t)(m0 + quad * 4 + r) * 512 + n] = clampf(acc[nt][r] + bv, 1e4f);
    }
}

// Diagnostic: encode ws_MiB into output if ws too small for any tier.
__global__ void diag_fill(float* out, int n, float v) {
    int i = blockIdx.x * blockDim.x + threadIdx.x;
    if (i < n) out[i] = v;
}

extern "C" void kernel_launch(void* const* d_in, const int* in_sizes, int n_in,
                              void* d_out, int out_size, void* d_ws, size_t ws_size,
                              hipStream_t stream)
{
    const float* x      = (const float*)d_in[0];
    const float* qkv_w  = (const float*)d_in[1];
    const float* qkv_b  = (const float*)d_in[2];
    const float* proj_w = (const float*)d_in[3];
    const float* proj_b = (const float*)d_in[4];
    float* out = (float*)d_out;

    int G = 0;  // heads per group; ws need = 8 + 3*G MiB
    if      (ws_size >= ((size_t)32 << 20)) G = 8;
    else if (ws_size >= ((size_t)20 << 20)) G = 4;
    else if (ws_size >= ((size_t)14 << 20)) G = 2;
    else if (ws_size >= ((size_t)11 << 20)) G = 1;
    if (!G) {
        diag_fill<<<(out_size + 255) / 256, 256, 0, stream>>>(
            out, out_size, 100.0f + (float)(ws_size >> 20));
        return;
    }

    ushort* o  = (ushort*)d_ws;                       // (B, L, C) bf16, 8 MiB
    ushort* q  = o + 4194304;                         // (B, G, L, hd)
    ushort* k  = q + (size_t)G * 524288;              // (B, G, L, hd)
    ushort* vt = k + (size_t)G * 524288;              // (B, G, hd, L)

    for (int h0 = 0; h0 < 8; h0 += G) {
        qkv_rope<<<dim3(128, 3 * G), 256, 0, stream>>>(x, qkv_w, qkv_b, q, k, vt, G, h0);
        flash_attn<<<dim3(64, 2 * G), 256, 0, stream>>>(q, k, vt, o, G, h0);
    }
    proj_gemm<<<dim3(128, 8), 256, 0, stream>>>(o, proj_w, proj_b, out);
}

// Round 4
// 778.924 us; speedup vs baseline: 1.0416x; 1.0416x over previous
//
#include <hip/hip_runtime.h>

// B=2, L=4096, C=512, H=8, hd=64. f32 in/out; bf16 MFMA compute.
// v4: transposed flash (S^T=K·Q^T, O^T=V^T·P^T) -> column softmax with 2
// swizzles/reduction, no __syncthreads (wave-private LDS transpose), 64-key
// chunks, pre-converted bf16 operands for the two GEMMs.

typedef __attribute__((ext_vector_type(8))) short short8;   // 8 bf16
typedef __attribute__((ext_vector_type(4))) float floatx4;  // MFMA C/D

#define MFMA(a, b, c) __builtin_amdgcn_mfma_f32_16x16x32_bf16((a), (b), (c), 0, 0, 0)
// Compiler fence: DS ops in a wave complete in order; this stops reordering.
#define MEM_FENCE() __asm__ volatile("" ::: "memory")

__device__ __forceinline__ unsigned short f2bf(float f) {
    unsigned int u = __builtin_bit_cast(unsigned int, f);
    return (unsigned short)((u + 0x7fffu + ((u >> 16) & 1u)) >> 16);  // RTNE
}
__device__ __forceinline__ unsigned int pack_bf16(float lo, float hi) {
    return ((unsigned int)f2bf(hi) << 16) | (unsigned int)f2bf(lo);
}

// f32 -> bf16 bulk conversion, 8 elems/thread.
__global__ __launch_bounds__(256) void conv_bf16(
    const float* __restrict__ src, ushort* __restrict__ dst, int n8)
{
    int i = blockIdx.x * blockDim.x + threadIdx.x;
    if (i >= n8) return;
    const float4* s = (const float4*)src + (size_t)i * 2;
    float4 a = s[0], b = s[1];
    short8 r;
    r[0] = (short)f2bf(a.x); r[1] = (short)f2bf(a.y);
    r[2] = (short)f2bf(a.z); r[3] = (short)f2bf(a.w);
    r[4] = (short)f2bf(b.x); r[5] = (short)f2bf(b.y);
    r[6] = (short)f2bf(b.z); r[7] = (short)f2bf(b.w);
    *(short8*)(dst + (size_t)i * 8) = r;
}

// ---------------------------------------------------------------------------
// qkv = xb @ wb.T + b for G heads from h0; RoPE q,k; q pre-scaled by 1/8;
// v stored transposed (hd, L). blockIdx.y: sec = y/G, head = h0 + y%G.
// ---------------------------------------------------------------------------
__global__ __launch_bounds__(256) void qkv_rope(
    const ushort* __restrict__ xb,    // (8192, 512) bf16
    const ushort* __restrict__ wb,    // (1536, 512) bf16
    const float* __restrict__ bias,   // (1536,) f32
    ushort* __restrict__ q, ushort* __restrict__ k, ushort* __restrict__ vt,
    int G, int h0)
{
    const int w_id = threadIdx.x >> 6;
    const int lane = threadIdx.x & 63;
    const int lr = lane & 15, quad = lane >> 4;
    const int m0 = blockIdx.x * 64 + w_id * 16;
    const int sec = blockIdx.y / G, hl = blockIdx.y % G;
    const int wc0 = sec * 512 + (h0 + hl) * 64;

    floatx4 acc[4] = {};
    const ushort* xrow = xb + (size_t)(m0 + lr) * 512 + quad * 8;
    for (int kk = 0; kk < 512; kk += 32) {
        short8 a = *(const short8*)(xrow + kk);
#pragma unroll
        for (int nt = 0; nt < 4; ++nt) {
            short8 b = *(const short8*)(wb + (size_t)(wc0 + nt * 16 + lr) * 512 + kk + quad * 8);
            acc[nt] = MFMA(a, b, acc[nt]);
        }
    }

#pragma unroll
    for (int nt = 0; nt < 4; ++nt) {
        const int d = nt * 16 + lr;
        const float bv = bias[wc0 + d];
#pragma unroll
        for (int r = 0; r < 4; ++r) {
            const int row = m0 + quad * 4 + r;
            const int b_ = row >> 12;
            const int pos = row & 4095;
            float val = acc[nt][r] + bv;
            const size_t bhl = (size_t)(b_ * G + hl);
            if (sec < 2) {
                float partner = __shfl_xor(val, 1);
                float invf = exp2f(-0.41524101186f * (float)(d & 31));
                float sv, cv;
                sincosf((float)pos * invf, &sv, &cv);
                float rh = (d & 1) ? partner : -partner;
                float rv = val * cv + rh * sv;
                if (sec == 0) rv *= 0.125f;         // fold softmax scale into q
                ushort* dst = (sec == 0) ? q : k;
                dst[(bhl * 4096 + pos) * 64 + d] = f2bf(rv);
            } else {
                vt[(bhl * 64 + d) * 4096 + pos] = f2bf(val);
            }
        }
    }
}

// ---------------------------------------------------------------------------
// Transposed flash attention. One wave = 16 queries (n-dim), chunks of 64 keys.
// S^T = K·Q^T (keys=m), column softmax (keys spread over quad×reg -> in-lane
// tree + xor16/xor32), P^T through wave-private LDS, O^T = V^T·P^T.
// ---------------------------------------------------------------------------
__global__ __launch_bounds__(256) void flash_attn(
    const ushort* __restrict__ q, const ushort* __restrict__ k,
    const ushort* __restrict__ vt, ushort* __restrict__ o,
    int G, int h0)
{
    // per-wave P^T staging: [query 0..15][key 0..63], row stride 72 elems
    // (144 B = 16*9: b128-aligned; 2-way-only bank aliasing on writes).
    __shared__ __align__(16) ushort plds[4][16 * 72];
    const int w_id = threadIdx.x >> 6;
    const int lane = threadIdx.x & 63;
    const int lr = lane & 15, quad = lane >> 4;
    const int bhl = blockIdx.y;
    const int b_ = bhl / G, hl = bhl % G;
    const int q0 = blockIdx.x * 64 + w_id * 16;

    const ushort* qp = q + (size_t)bhl * 262144;
    const ushort* kp = k + (size_t)bhl * 262144;
    const ushort* vp = vt + (size_t)bhl * 262144;
    ushort* op = o + (size_t)b_ * 4096 * 512 + (size_t)(h0 + hl) * 64;
    char* pw = (char*)&plds[w_id][0];

    // Q^T B-frags (q pre-scaled by 1/8): B[k=d][n=query=lr]
    short8 qf0 = *(const short8*)(qp + (size_t)(q0 + lr) * 64 + quad * 8);
    short8 qf1 = *(const short8*)(qp + (size_t)(q0 + lr) * 64 + 32 + quad * 8);

    floatx4 oacc[4] = {};               // O^T: d-tile dt, d=dt*16+quad*4+r, col=lr
    float m = -INFINITY, l = 0.f;       // per-query (col lr), uniform over quads

    for (int kk = 0; kk < 4096; kk += 64) {
        // Prefetch K (4 key-tiles x 2 d-chunks) and V^T (4 d-tiles x 2 k-chunks)
        short8 ka[4][2], va[4][2];
#pragma unroll
        for (int t = 0; t < 4; ++t) {
            const ushort* kb = kp + (size_t)(kk + t * 16 + lr) * 64 + quad * 8;
            ka[t][0] = *(const short8*)kb;
            ka[t][1] = *(const short8*)(kb + 32);
            const ushort* vb = vp + (size_t)(t * 16 + lr) * 4096 + kk + quad * 8;
            va[t][0] = *(const short8*)vb;
            va[t][1] = *(const short8*)(vb + 32);
        }
        // S^T tiles: st[t] = keys 16t+quad*4+r (rows), queries lr (cols)
        floatx4 st[4];
#pragma unroll
        for (int t = 0; t < 4; ++t) {
            floatx4 s = {};
            s = MFMA(ka[t][0], qf0, s);
            s = MFMA(ka[t][1], qf1, s);
            st[t] = s;
        }
        // column max over 16 in-lane values + cross-quad
        float mx = fmaxf(fmaxf(fmaxf(st[0][0], st[0][1]), fmaxf(st[0][2], st[0][3])),
                         fmaxf(fmaxf(st[1][0], st[1][1]), fmaxf(st[1][2], st[1][3])));
        mx = fmaxf(mx, fmaxf(fmaxf(fmaxf(st[2][0], st[2][1]), fmaxf(st[2][2], st[2][3])),
                             fmaxf(fmaxf(st[3][0], st[3][1]), fmaxf(st[3][2], st[3][3]))));
        mx = fmaxf(mx, __shfl_xor(mx, 16));
        mx = fmaxf(mx, __shfl_xor(mx, 32));
        float mn = fmaxf(m, mx);
        float alpha = __expf(m - mn);   // first chunk: exp(-inf) = 0
        m = mn;

        MEM_FENCE();  // prior iter's ds_read must precede these overwrites
        float rs = 0.f;
#pragma unroll
        for (int t = 0; t < 4; ++t) {
            float p0 = __expf(st[t][0] - mn), p1 = __expf(st[t][1] - mn);
            float p2 = __expf(st[t][2] - mn), p3 = __expf(st[t][3] - mn);
            rs += (p0 + p1) + (p2 + p3);
            uint2 u = { pack_bf16(p0, p1), pack_bf16(p2, p3) };
            // element (query lr, keys 16t+quad*4 .. +3)
            *(uint2*)(pw + lr * 144 + t * 32 + quad * 8) = u;
        }
        rs += __shfl_xor(rs, 16);
        rs += __shfl_xor(rs, 32);
        l = l * alpha + rs;
#pragma unroll
        for (int t = 0; t < 4; ++t)
#pragma unroll
            for (int r = 0; r < 4; ++r) oacc[t][r] *= alpha;

        MEM_FENCE();  // ds_reads below must follow the writes above
        // O^T += V^T · P^T over two 32-key chunks
#pragma unroll
        for (int ch = 0; ch < 2; ++ch) {
            short8 pf = *(const short8*)(pw + lr * 144 + ch * 64 + quad * 16);
#pragma unroll
            for (int dt = 0; dt < 4; ++dt)
                oacc[dt] = MFMA(va[dt][ch], pf, oacc[dt]);
        }
    }

    float inv = 1.0f / l;
#pragma unroll
    for (int dt = 0; dt < 4; ++dt)
#pragma unroll
        for (int c = 0; c < 2; ++c) {
            unsigned int u = pack_bf16(oacc[dt][2 * c] * inv, oacc[dt][2 * c + 1] * inv);
            *(unsigned int*)(op + (size_t)(q0 + lr) * 512 + dt * 16 + quad * 4 + c * 2) = u;
        }
}

// ---------------------------------------------------------------------------
// out(f32) = o(bf16) @ pwb.T + proj_b
// ---------------------------------------------------------------------------
__global__ __launch_bounds__(256) void proj_gemm(
    const ushort* __restrict__ o,      // (8192, 512) bf16
    const ushort* __restrict__ wb,     // (512, 512) bf16
    const float* __restrict__ bias,    // (512,) f32
    float* __restrict__ out)           // (8192, 512) f32
{
    const int w_id = threadIdx.x >> 6;
    const int lane = threadIdx.x & 63;
    const int lr = lane & 15, quad = lane >> 4;
    const int m0 = blockIdx.x * 64 + w_id * 16;
    const int n0 = blockIdx.y * 64;

    floatx4 acc[4] = {};
    const ushort* orow = o + (size_t)(m0 + lr) * 512 + quad * 8;
    for (int kk = 0; kk < 512; kk += 32) {
        short8 a = *(const short8*)(orow + kk);
#pragma unroll
        for (int nt = 0; nt < 4; ++nt) {
            short8 b = *(const short8*)(wb + (size_t)(n0 + nt * 16 + lr) * 512 + kk + quad * 8);
            acc[nt] = MFMA(a, b, acc[nt]);
        }
    }
#pragma unroll
    for (int nt = 0; nt < 4; ++nt) {
        const int n = n0 + nt * 16 + lr;
        const float bv = bias[n];
#pragma unroll
        for (int r = 0; r < 4; ++r)
            out[(size_t)(m0 + quad * 4 + r) * 512 + n] = acc[nt][r] + bv;
    }
}

extern "C" void kernel_launch(void* const* d_in, const int* in_sizes, int n_in,
                              void* d_out, int out_size, void* d_ws, size_t ws_size,
                              hipStream_t stream)
{
    const float* x      = (const float*)d_in[0];
    const float* qkv_w  = (const float*)d_in[1];
    const float* qkv_b  = (const float*)d_in[2];
    const float* proj_w = (const float*)d_in[3];
    const float* proj_b = (const float*)d_in[4];
    float* out = (float*)d_out;

    const size_t MB = (size_t)1 << 20;
    ushort* base = (ushort*)d_ws;
    int G;
    ushort *xb, *o, *wb, *pwb, *q, *k, *vt;
    if (ws_size >= 34 * MB) {
        // G=8: single group -> o can alias xb (xb dead before flash runs)
        G = 8;
        xb = base; o = base;                 // 8 MiB shared
        wb  = base + 4194304;                // 1.5 MiB
        pwb = wb + 786432;                   // 0.5 MiB
        q   = pwb + 262144;
        k   = q + (size_t)G * 524288;
        vt  = k + (size_t)G * 524288;
    } else {
        // multi-group: xb alive across flash -> separate o. 16+2+3G MiB.
        G = (ws_size >= 30 * MB) ? 4 : (ws_size >= 24 * MB) ? 2 : 1;
        xb  = base;                          // 8 MiB
        o   = base + 4194304;                // 8 MiB
        wb  = o + 4194304;
        pwb = wb + 786432;
        q   = pwb + 262144;
        k   = q + (size_t)G * 524288;
        vt  = k + (size_t)G * 524288;
    }

    conv_bf16<<<2048, 256, 0, stream>>>(x, xb, 524288);
    conv_bf16<<<384, 256, 0, stream>>>(qkv_w, wb, 98304);
    conv_bf16<<<128, 256, 0, stream>>>(proj_w, pwb, 32768);

    for (int h0 = 0; h0 < 8; h0 += G) {
        qkv_rope<<<dim3(128, 3 * G), 256, 0, stream>>>(xb, wb, qkv_b, q, k, vt, G, h0);
        flash_attn<<<dim3(64, 2 * G), 256, 0, stream>>>(q, k, vt, o, G, h0);
    }
    proj_gemm<<<dim3(128, 8), 256, 0, stream>>>(o, proj_w ? pwb : pwb, proj_b, out);
}

// Round 5
// 513.150 us; speedup vs baseline: 1.5811x; 1.5179x over previous
//
#include <hip/hip_runtime.h>

// B=2, L=4096, C=512, H=8, hd=64. f32 in/out; bf16 MFMA compute.
// v5 flash: no-max softmax (shift-invariant, exp(|x|<~40) safe in f32),
// 32 queries/wave (2 n-tiles), key-range split across wave pairs with
// LDS merge of unnormalized (O, l). Zero per-iter cross-lane ops.

typedef __attribute__((ext_vector_type(8))) short short8;   // 8 bf16
typedef __attribute__((ext_vector_type(4))) float floatx4;  // MFMA C/D

#define MFMA(a, b, c) __builtin_amdgcn_mfma_f32_16x16x32_bf16((a), (b), (c), 0, 0, 0)
#define MEM_FENCE() __asm__ volatile("" ::: "memory")

__device__ __forceinline__ unsigned short f2bf(float f) {
    unsigned int u = __builtin_bit_cast(unsigned int, f);
    return (unsigned short)((u + 0x7fffu + ((u >> 16) & 1u)) >> 16);  // RTNE
}
__device__ __forceinline__ unsigned int pack_bf16(float lo, float hi) {
    return ((unsigned int)f2bf(hi) << 16) | (unsigned int)f2bf(lo);
}

__global__ __launch_bounds__(256) void conv_bf16(
    const float* __restrict__ src, ushort* __restrict__ dst, int n8)
{
    int i = blockIdx.x * blockDim.x + threadIdx.x;
    if (i >= n8) return;
    const float4* s = (const float4*)src + (size_t)i * 2;
    float4 a = s[0], b = s[1];
    short8 r;
    r[0] = (short)f2bf(a.x); r[1] = (short)f2bf(a.y);
    r[2] = (short)f2bf(a.z); r[3] = (short)f2bf(a.w);
    r[4] = (short)f2bf(b.x); r[5] = (short)f2bf(b.y);
    r[6] = (short)f2bf(b.z); r[7] = (short)f2bf(b.w);
    *(short8*)(dst + (size_t)i * 8) = r;
}

// ---------------------------------------------------------------------------
// qkv = xb @ wb.T + b for G heads from h0; RoPE q,k; q pre-scaled by 1/8;
// v stored transposed (hd, L).
// ---------------------------------------------------------------------------
__global__ __launch_bounds__(256) void qkv_rope(
    const ushort* __restrict__ xb,    // (8192, 512) bf16
    const ushort* __restrict__ wb,    // (1536, 512) bf16
    const float* __restrict__ bias,   // (1536,) f32
    ushort* __restrict__ q, ushort* __restrict__ k, ushort* __restrict__ vt,
    int G, int h0)
{
    const int w_id = threadIdx.x >> 6;
    const int lane = threadIdx.x & 63;
    const int lr = lane & 15, quad = lane >> 4;
    const int m0 = blockIdx.x * 64 + w_id * 16;
    const int sec = blockIdx.y / G, hl = blockIdx.y % G;
    const int wc0 = sec * 512 + (h0 + hl) * 64;

    floatx4 acc[4] = {};
    const ushort* xrow = xb + (size_t)(m0 + lr) * 512 + quad * 8;
    for (int kk = 0; kk < 512; kk += 32) {
        short8 a = *(const short8*)(xrow + kk);
#pragma unroll
        for (int nt = 0; nt < 4; ++nt) {
            short8 b = *(const short8*)(wb + (size_t)(wc0 + nt * 16 + lr) * 512 + kk + quad * 8);
            acc[nt] = MFMA(a, b, acc[nt]);
        }
    }

#pragma unroll
    for (int nt = 0; nt < 4; ++nt) {
        const int d = nt * 16 + lr;
        const float bv = bias[wc0 + d];
#pragma unroll
        for (int r = 0; r < 4; ++r) {
            const int row = m0 + quad * 4 + r;
            const int b_ = row >> 12;
            const int pos = row & 4095;
            float val = acc[nt][r] + bv;
            const size_t bhl = (size_t)(b_ * G + hl);
            if (sec < 2) {
                float partner = __shfl_xor(val, 1);
                float invf = exp2f(-0.41524101186f * (float)(d & 31));
                float sv, cv;
                sincosf((float)pos * invf, &sv, &cv);
                float rh = (d & 1) ? partner : -partner;
                float rv = val * cv + rh * sv;
                if (sec == 0) rv *= 0.125f;
                ushort* dst = (sec == 0) ? q : k;
                dst[(bhl * 4096 + pos) * 64 + d] = f2bf(rv);
            } else {
                vt[(bhl * 64 + d) * 4096 + pos] = f2bf(val);
            }
        }
    }
}

// ---------------------------------------------------------------------------
// Flash v5. Block = 4 waves: w_id = qg + 2*kh. Each wave: 32 queries
// (q0 = bx*64 + qg*32, 2 n-tiles), keys [kh*2048, kh*2048+2048) in 32-chunks.
// S^T = K·Q^T; P = exp(S^T) (no max); P^T via wave-private LDS; O^T += V^T·P^T.
// kh-pair merges unnormalized (O,l) through LDS; kh==0 normalizes and stores.
// ---------------------------------------------------------------------------
__global__ __launch_bounds__(256) void flash_attn(
    const ushort* __restrict__ q, const ushort* __restrict__ k,
    const ushort* __restrict__ vt, ushort* __restrict__ o,
    int G, int h0)
{
    __shared__ __align__(16) ushort plds[4][32 * 72];   // P: 32 rows x 144B
    __shared__ float mbuf[2][64 * 32 + 32];             // merge: O^T + l per qg
    const int w_id = threadIdx.x >> 6;
    const int lane = threadIdx.x & 63;
    const int lr = lane & 15, quad = lane >> 4;
    const int qg = w_id & 1, kh = w_id >> 1;
    const int bhl = blockIdx.y;
    const int b_ = bhl / G, hl = bhl % G;
    const int q0 = blockIdx.x * 64 + qg * 32;

    const ushort* qp = q + (size_t)bhl * 262144;
    const ushort* kp = k + (size_t)bhl * 262144;
    const ushort* vp = vt + (size_t)bhl * 262144;
    ushort* op = o + (size_t)b_ * 4096 * 512 + (size_t)(h0 + hl) * 64;
    char* pw = (char*)&plds[w_id][0];

    // Q^T B-frags: qf[n][c] = B[k=32c..][n=query 16n+lr]
    short8 qf[2][2];
#pragma unroll
    for (int n = 0; n < 2; ++n) {
        const ushort* qb = qp + (size_t)(q0 + 16 * n + lr) * 64 + quad * 8;
        qf[n][0] = *(const short8*)qb;
        qf[n][1] = *(const short8*)(qb + 32);
    }

    floatx4 oacc[4][2] = {};   // [d-tile][n-tile]
    float l0 = 0.f, l1 = 0.f;  // per-query unnormalized denom (in-lane partial)

    const int kbase = kh * 2048;
    for (int it = 0; it < 64; ++it) {
        const int kk = kbase + it * 32;
        short8 ka[2][2], va[4];
#pragma unroll
        for (int t = 0; t < 2; ++t) {
            const ushort* kb = kp + (size_t)(kk + 16 * t + lr) * 64 + quad * 8;
            ka[t][0] = *(const short8*)kb;
            ka[t][1] = *(const short8*)(kb + 32);
        }
#pragma unroll
        for (int dt = 0; dt < 4; ++dt)
            va[dt] = *(const short8*)(vp + (size_t)(16 * dt + lr) * 4096 + kk + quad * 8);

        // S^T tiles [key-tile][n-tile]
        floatx4 st[2][2];
#pragma unroll
        for (int t = 0; t < 2; ++t)
#pragma unroll
            for (int n = 0; n < 2; ++n) {
                floatx4 s = {};
                s = MFMA(ka[t][0], qf[n][0], s);
                s = MFMA(ka[t][1], qf[n][1], s);
                st[t][n] = s;
            }

        MEM_FENCE();  // prior iter's ds_reads precede overwrite (in-order DS)
#pragma unroll
        for (int t = 0; t < 2; ++t)
#pragma unroll
            for (int n = 0; n < 2; ++n) {
                float p0 = __expf(st[t][n][0]), p1 = __expf(st[t][n][1]);
                float p2 = __expf(st[t][n][2]), p3 = __expf(st[t][n][3]);
                float s4 = (p0 + p1) + (p2 + p3);
                if (n == 0) l0 += s4; else l1 += s4;
                uint2 u = { pack_bf16(p0, p1), pack_bf16(p2, p3) };
                *(uint2*)(pw + (16 * n + lr) * 144 + t * 32 + quad * 8) = u;
            }
        MEM_FENCE();
#pragma unroll
        for (int n = 0; n < 2; ++n) {
            short8 pf = *(const short8*)(pw + (16 * n + lr) * 144 + quad * 16);
#pragma unroll
            for (int dt = 0; dt < 4; ++dt)
                oacc[dt][n] = MFMA(va[dt], pf, oacc[dt][n]);
        }
    }

    // reduce l across quads (queries live in lr; quads hold disjoint keys)
    l0 += __shfl_xor(l0, 16); l0 += __shfl_xor(l0, 32);
    l1 += __shfl_xor(l1, 16); l1 += __shfl_xor(l1, 32);

    // kh=1 publishes unnormalized O^T and l; kh=0 merges, normalizes, stores.
    if (kh == 1) {
#pragma unroll
        for (int dt = 0; dt < 4; ++dt)
#pragma unroll
            for (int n = 0; n < 2; ++n)
#pragma unroll
                for (int r = 0; r < 4; ++r)
                    mbuf[qg][(16 * dt + 4 * quad + r) * 32 + 16 * n + lr] = oacc[dt][n][r];
        if (quad == 0) {
            mbuf[qg][2048 + lr] = l0;
            mbuf[qg][2048 + 16 + lr] = l1;
        }
    }
    __syncthreads();
    if (kh == 0) {
        float inv0 = 1.0f / (l0 + mbuf[qg][2048 + lr]);
        float inv1 = 1.0f / (l1 + mbuf[qg][2048 + 16 + lr]);
#pragma unroll
        for (int dt = 0; dt < 4; ++dt)
#pragma unroll
            for (int n = 0; n < 2; ++n) {
                float inv = n ? inv1 : inv0;
                float v0 = (oacc[dt][n][0] + mbuf[qg][(16 * dt + 4 * quad + 0) * 32 + 16 * n + lr]) * inv;
                float v1 = (oacc[dt][n][1] + mbuf[qg][(16 * dt + 4 * quad + 1) * 32 + 16 * n + lr]) * inv;
                float v2 = (oacc[dt][n][2] + mbuf[qg][(16 * dt + 4 * quad + 2) * 32 + 16 * n + lr]) * inv;
                float v3 = (oacc[dt][n][3] + mbuf[qg][(16 * dt + 4 * quad + 3) * 32 + 16 * n + lr]) * inv;
                uint2 u = { pack_bf16(v0, v1), pack_bf16(v2, v3) };
                *(uint2*)(op + (size_t)(q0 + 16 * n + lr) * 512 + 16 * dt + 4 * quad) = u;
            }
    }
}

// ---------------------------------------------------------------------------
// out(f32) = o(bf16) @ wb.T + proj_b
// ---------------------------------------------------------------------------
__global__ __launch_bounds__(256) void proj_gemm(
    const ushort* __restrict__ o,      // (8192, 512) bf16
    const ushort* __restrict__ wb,     // (512, 512) bf16
    const float* __restrict__ bias,    // (512,) f32
    float* __restrict__ out)           // (8192, 512) f32
{
    const int w_id = threadIdx.x >> 6;
    const int lane = threadIdx.x & 63;
    const int lr = lane & 15, quad = lane >> 4;
    const int m0 = blockIdx.x * 64 + w_id * 16;
    const int n0 = blockIdx.y * 64;

    floatx4 acc[4] = {};
    const ushort* orow = o + (size_t)(m0 + lr) * 512 + quad * 8;
    for (int kk = 0; kk < 512; kk += 32) {
        short8 a = *(const short8*)(orow + kk);
#pragma unroll
        for (int nt = 0; nt < 4; ++nt) {
            short8 b = *(const short8*)(wb + (size_t)(n0 + nt * 16 + lr) * 512 + kk + quad * 8);
            acc[nt] = MFMA(a, b, acc[nt]);
        }
    }
#pragma unroll
    for (int nt = 0; nt < 4; ++nt) {
        const int n = n0 + nt * 16 + lr;
        const float bv = bias[n];
#pragma unroll
        for (int r = 0; r < 4; ++r)
            out[(size_t)(m0 + quad * 4 + r) * 512 + n] = acc[nt][r] + bv;
    }
}

extern "C" void kernel_launch(void* const* d_in, const int* in_sizes, int n_in,
                              void* d_out, int out_size, void* d_ws, size_t ws_size,
                              hipStream_t stream)
{
    const float* x      = (const float*)d_in[0];
    const float* qkv_w  = (const float*)d_in[1];
    const float* qkv_b  = (const float*)d_in[2];
    const float* proj_w = (const float*)d_in[3];
    const float* proj_b = (const float*)d_in[4];
    float* out = (float*)d_out;

    const size_t MB = (size_t)1 << 20;
    ushort* base = (ushort*)d_ws;
    int G;
    ushort *xb, *o, *wb, *pwb, *q, *k, *vt;
    if (ws_size >= 34 * MB) {
        // G=8: single group -> o aliases xb (xb dead before flash runs)
        G = 8;
        xb = base; o = base;                 // 8 MiB shared
        wb  = base + 4194304;                // 1.5 MiB
        pwb = wb + 786432;                   // 0.5 MiB
        q   = pwb + 262144;
        k   = q + (size_t)G * 524288;
        vt  = k + (size_t)G * 524288;
    } else {
        G = (ws_size >= 30 * MB) ? 4 : (ws_size >= 24 * MB) ? 2 : 1;
        xb  = base;                          // 8 MiB
        o   = base + 4194304;                // 8 MiB
        wb  = o + 4194304;
        pwb = wb + 786432;
        q   = pwb + 262144;
        k   = q + (size_t)G * 524288;
        vt  = k + (size_t)G * 524288;
    }

    conv_bf16<<<2048, 256, 0, stream>>>(x, xb, 524288);
    conv_bf16<<<384, 256, 0, stream>>>(qkv_w, wb, 98304);
    conv_bf16<<<128, 256, 0, stream>>>(proj_w, pwb, 32768);

    for (int h0 = 0; h0 < 8; h0 += G) {
        qkv_rope<<<dim3(128, 3 * G), 256, 0, stream>>>(xb, wb, qkv_b, q, k, vt, G, h0);
        flash_attn<<<dim3(64, 2 * G), 256, 0, stream>>>(q, k, vt, o, G, h0);
    }
    proj_gemm<<<dim3(128, 8), 256, 0, stream>>>(o, pwb, proj_b, out);
}